// Round 4
// baseline (265.405 us; speedup 1.0000x reference)
//
#include <hip/hip_runtime.h>

#define EPSV 1e-5f
constexpr int Bb = 4, Cc = 64, Nn = 40960, Kk = 16, Dd = 128;
constexpr int G = 4;                       // point-tiles per block in passC/passB (even!)
constexpr int TPB = Nn / 16;               // tiles per batch = 2560
constexpr int GB_BPB = 640;                // gather blocks per batch (even)
constexpr int GB_NG = Nn / (16 * GB_BPB);  // 16-pt groups per gather block = 4

typedef float f32x4 __attribute__((ext_vector_type(4)));
typedef __bf16 bf16x8 __attribute__((ext_vector_type(8)));
typedef unsigned short us8 __attribute__((ext_vector_type(8)));
typedef unsigned short us4 __attribute__((ext_vector_type(4)));

__device__ inline unsigned short f2bf(float x) {
    unsigned u = __builtin_bit_cast(unsigned, x);
    u += 0x7FFFu + ((u >> 16) & 1u);   // RNE
    return (unsigned short)(u >> 16);
}

// ---------------------------------------------------------------------------
// Prep: fold BN scale into bf16 weights, precompute shifts.
__global__ __launch_bounds__(256) void prep_weights(
    const float* __restrict__ w1, const float* __restrict__ g1, const float* __restrict__ b1,
    const float* __restrict__ m1, const float* __restrict__ v1,
    const float* __restrict__ w2, const float* __restrict__ g2, const float* __restrict__ b2,
    const float* __restrict__ m2, const float* __restrict__ v2,
    const float* __restrict__ w3, const float* __restrict__ g3, const float* __restrict__ b3,
    const float* __restrict__ m3, const float* __restrict__ v3,
    unsigned short* __restrict__ w1s, unsigned short* __restrict__ w2s, unsigned short* __restrict__ w3s,
    float* __restrict__ sh1, float* __restrict__ sh2, float* __restrict__ sh3) {
    const int e = blockIdx.x * 256 + threadIdx.x;
    if (e < 4096) {
        const int o = e >> 6;
        const float sc = g1[o] * rsqrtf(v1[o] + EPSV);
        w1s[e] = f2bf(w1[e] * sc);
    } else if (e < 12288) {
        const int i = e - 4096, o = i >> 6;
        const float sc = g2[o] * rsqrtf(v2[o] + EPSV);
        w2s[i] = f2bf(w2[i] * sc);
    } else if (e < 20480) {
        const int i = e - 12288, o = i >> 6;
        const float sc = g3[o] * rsqrtf(v3[o] + EPSV);
        w3s[i] = f2bf(w3[i] * sc);
    }
    if (e < 64) sh1[e] = b1[e] - m1[e] * (g1[e] * rsqrtf(v1[e] + EPSV));
    else if (e < 192) { const int d = e - 64;  sh2[d] = b2[d] - m2[d] * (g2[d] * rsqrtf(v2[d] + EPSV)); }
    else if (e < 320) { const int d = e - 192; sh3[d] = b3[d] - m3[d] * (g3[d] * rsqrtf(v3[d] + EPSV)); }
}

// ---------------------------------------------------------------------------
// Pass A: G1 = relu(sc1 * (W1 . f) + sh1), stored channel-SPLIT:
// G1a[b][n][32ch] / G1b[b][n][32ch] bf16 (2.62 MB per batch per half -> each
// half fits one XCD's 4 MiB L2 during the gather phase).
__global__ __launch_bounds__(256) void passA(const float* __restrict__ f,
                                             const unsigned short* __restrict__ w1s,
                                             const float* __restrict__ sh1,
                                             unsigned short* __restrict__ G1a,
                                             unsigned short* __restrict__ G1b) {
    __shared__ float s[64 * 65];                            // [ch][pt]
    __shared__ __attribute__((aligned(16))) unsigned short sg1[64 * 72];  // [pt][ch]

    const int tid = threadIdx.x, w = tid >> 6, lane = tid & 63;
    const int c15 = lane & 15, q = lane >> 4;
    const int b = blockIdx.x / 640;
    const int n0 = (blockIdx.x % 640) * 64;

    // load fp32 tile: [64 ch][64 pts]
    const float* src = f + ((size_t)b * Cc + w * 16) * Nn + n0 + lane;
#pragma unroll
    for (int i = 0; i < 16; ++i) s[(w * 16 + i) * 65 + lane] = src[(size_t)i * Nn];

    // weight B-frags: out-channel o1 = w*16 + c15
    const int o1 = w * 16 + c15;
    const float sh1v = sh1[o1];
    bf16x8 bw1[2];
#pragma unroll
    for (int ks = 0; ks < 2; ++ks)
        bw1[ks] = __builtin_bit_cast(bf16x8, *(const uint4*)(w1s + o1 * 64 + ks * 32 + q * 8));
    __syncthreads();

#pragma unroll
    for (int mt = 0; mt < 4; ++mt) {
        const int pt = mt * 16 + c15;
        us8 A0, A1;
#pragma unroll
        for (int j = 0; j < 8; ++j) A0[j] = f2bf(s[(q * 8 + j) * 65 + pt]);
#pragma unroll
        for (int j = 0; j < 8; ++j) A1[j] = f2bf(s[(32 + q * 8 + j) * 65 + pt]);
        f32x4 g = {0.f, 0.f, 0.f, 0.f};
        g = __builtin_amdgcn_mfma_f32_16x16x32_bf16(__builtin_bit_cast(bf16x8, A0), bw1[0], g, 0, 0, 0);
        g = __builtin_amdgcn_mfma_f32_16x16x32_bf16(__builtin_bit_cast(bf16x8, A1), bw1[1], g, 0, 0, 0);
#pragma unroll
        for (int r = 0; r < 4; ++r)
            sg1[(mt * 16 + q * 4 + r) * 72 + o1] = f2bf(fmaxf(g[r] + sh1v, 0.f));
    }
    __syncthreads();

    // coalesced split store: thread (p = tid>>2, ck = tid&3) writes 32 B
    // (ch [16ck,16ck+16)) of row p into the matching half.
    {
        const int p = tid >> 2, ck = tid & 3;
        const uint4 v0 = *(const uint4*)(sg1 + p * 72 + ck * 16);
        const uint4 v1 = *(const uint4*)(sg1 + p * 72 + ck * 16 + 8);
        unsigned short* half = (ck < 2) ? G1a : G1b;
        unsigned short* dst = half + ((size_t)b * Nn + n0 + p) * 32 + (ck & 1) * 16;
        *(uint4*)dst = v0;
        *(uint4*)(dst + 8) = v1;
    }
}

// ---------------------------------------------------------------------------
// gatherH: h1[:, :, hofs..hofs+32) = sum_k G1h[idx[k]] for one channel half.
// XCD-batch affinity: xcd = bid&7, batch = xcd>>1 -> each XCD gathers from
// ONE batch's half (2.62 MB), which is L2-resident. Kernel boundary keeps
// only one half live across the whole GPU at a time.
// Thread (pg, rg, chg): point pg, k-parity rg, 4-channel chunk chg; 8 x 8B
// gather loads per group, shfl_xor(8) combines k-parities.
__global__ __launch_bounds__(256) void gatherH(
    const unsigned short* __restrict__ G1h,   // [B][N][32]
    const int* __restrict__ idx,
    unsigned short* __restrict__ h1,          // [B][N][64]
    const int hofs) {
    const int tid = threadIdx.x;
    const int pg = tid >> 4, cg = tid & 15;
    const int rg = cg >> 3, chg = cg & 7;
    const int bid = blockIdx.x;
    const int xcd = bid & 7;
    const int b = xcd >> 1;
    const int j = ((bid >> 3) << 1) | (xcd & 1);     // 0..GB_BPB-1

    const unsigned short* Gb = G1h + (size_t)b * Nn * 32;
    unsigned short* h1b = h1 + (size_t)b * Nn * 64 + hofs;
    const int* idxb = idx + (size_t)b * Nn * Kk;

#pragma unroll
    for (int it = 0; it < GB_NG; ++it) {
        const int n0 = (j * GB_NG + it) * 16;
        const int myidx = __builtin_nontemporal_load(idxb + (size_t)n0 * Kk + tid);
        float a0 = 0.f, a1 = 0.f, a2 = 0.f, a3 = 0.f;
#pragma unroll
        for (int kk = 0; kk < 8; ++kk) {
            const int nb = __shfl(myidx, (pg & 3) * 16 + kk * 2 + rg, 64);
            const uint2 d2 = *(const uint2*)(Gb + (size_t)nb * 32 + chg * 4);
            a0 += __builtin_bit_cast(float, d2.x << 16);
            a1 += __builtin_bit_cast(float, d2.x & 0xffff0000u);
            a2 += __builtin_bit_cast(float, d2.y << 16);
            a3 += __builtin_bit_cast(float, d2.y & 0xffff0000u);
        }
        a0 += __shfl_xor(a0, 8, 64);
        a1 += __shfl_xor(a1, 8, 64);
        a2 += __shfl_xor(a2, 8, 64);
        a3 += __shfl_xor(a3, 8, 64);
        if (rg == 0) {
            const unsigned lo = (unsigned)f2bf(a0) | ((unsigned)f2bf(a1) << 16);
            const unsigned hi = (unsigned)f2bf(a2) | ((unsigned)f2bf(a3) << 16);
            const unsigned long long v = (unsigned long long)lo | ((unsigned long long)hi << 32);
            __builtin_nontemporal_store(v,
                (unsigned long long*)(h1b + (size_t)(n0 + pg) * 64 + chg * 4));
        }
    }
}

// ---------------------------------------------------------------------------
// passC: gather-free streaming MFMA. A-frags read directly from h1
// (sequential, L1-shared across the 4 waves); W2.h1 + W3.f_own, BN+ReLU,
// pair-buffered full-line nt-store epilogue. 1 barrier-pair per 2 tiles.
__global__ __launch_bounds__(256, 4) void passC(
    const unsigned short* __restrict__ h1, const float* __restrict__ f,
    const unsigned short* __restrict__ w2s, const unsigned short* __restrict__ w3s,
    const float* __restrict__ sh2, const float* __restrict__ sh3,
    float* __restrict__ out) {
    __shared__ float s_out[32 * 133];                                       // 17024 B

    const int tid  = threadIdx.x;
    const int wave = tid >> 6;
    const int lane = tid & 63;
    const int c15  = lane & 15;
    const int q    = lane >> 4;

    const int t0  = blockIdx.x * G;
    const int b   = t0 / TPB;
    const int nb0 = (t0 - b * TPB) * 16;

    float sh2v[2], sh3v[2];
    bf16x8 bw2[2][2], bw3[2][2];
#pragma unroll
    for (int nt = 0; nt < 2; ++nt) {
        const int d = wave * 32 + nt * 16 + c15;
        sh2v[nt] = sh2[d];
        sh3v[nt] = sh3[d];
#pragma unroll
        for (int ks = 0; ks < 2; ++ks) {
            bw2[nt][ks] = __builtin_bit_cast(bf16x8, *(const uint4*)(w2s + d * 64 + ks * 32 + q * 8));
            bw3[nt][ks] = __builtin_bit_cast(bf16x8, *(const uint4*)(w3s + d * 64 + ks * 32 + q * 8));
        }
    }

    const float* fb0 = f + (size_t)b * Cc * Nn;
    const unsigned short* h1b = h1 + (size_t)b * Nn * 64;

    for (int g = 0; g < G; ++g) {
        const int n0 = nb0 + g * 16;

        // own-feature A-frags (strided fp32 -> bf16)
        const float* fown = fb0 + n0 + c15;
        us8 F0, F1;
#pragma unroll
        for (int jj = 0; jj < 8; ++jj) F0[jj] = f2bf(fown[(size_t)(q * 8 + jj) * Nn]);
#pragma unroll
        for (int jj = 0; jj < 8; ++jj) F1[jj] = f2bf(fown[(size_t)(32 + q * 8 + jj) * Nn]);

        // h1 A-frags straight from global (row 128 B, fully consumed per wave)
        const unsigned short* h1row = h1b + (size_t)(n0 + c15) * 64;
        const bf16x8 ah0 = __builtin_bit_cast(bf16x8, *(const uint4*)(h1row + q * 8));
        const bf16x8 ah1 = __builtin_bit_cast(bf16x8, *(const uint4*)(h1row + 32 + q * 8));
        const bf16x8 af0 = __builtin_bit_cast(bf16x8, F0);
        const bf16x8 af1 = __builtin_bit_cast(bf16x8, F1);

        const int prow = (g & 1) * 16;
#pragma unroll
        for (int nt = 0; nt < 2; ++nt) {
            f32x4 h2 = {sh2v[nt], sh2v[nt], sh2v[nt], sh2v[nt]};
            f32x4 s3 = {sh3v[nt], sh3v[nt], sh3v[nt], sh3v[nt]};
            h2 = __builtin_amdgcn_mfma_f32_16x16x32_bf16(ah0, bw2[nt][0], h2, 0, 0, 0);
            h2 = __builtin_amdgcn_mfma_f32_16x16x32_bf16(ah1, bw2[nt][1], h2, 0, 0, 0);
            s3 = __builtin_amdgcn_mfma_f32_16x16x32_bf16(af0, bw3[nt][0], s3, 0, 0, 0);
            s3 = __builtin_amdgcn_mfma_f32_16x16x32_bf16(af1, bw3[nt][1], s3, 0, 0, 0);
            const int d = wave * 32 + nt * 16 + c15;
#pragma unroll
            for (int r = 0; r < 4; ++r)
                s_out[(prow + q * 4 + r) * 133 + d] = fmaxf(h2[r], 0.f) + fmaxf(s3[r], 0.f);
        }

        if (g & 1) {
            __syncthreads();                 // all waves' s_out rows 0..31 visible
            const int np = n0 - 16;          // pair base point (128-B line aligned)
            const int dd = tid >> 3;
            const int ck = tid & 7;
#pragma unroll
            for (int r4 = 0; r4 < 4; ++r4) {
                const int d = r4 * 32 + dd;
                f32x4 v;
#pragma unroll
                for (int i = 0; i < 4; ++i) v[i] = s_out[(ck * 4 + i) * 133 + d];
                __builtin_nontemporal_store(v, (f32x4*)(out + ((size_t)b * Dd + d) * Nn + np + ck * 4));
            }
            __syncthreads();                 // store reads done before rows 0..15 reused
        }
    }
}

// ---------------------------------------------------------------------------
// Fallback fused passB (round-3 proven structure, adapted to split G1 layout)
// — used only if ws_size can't hold the h1 buffer.
__global__ __launch_bounds__(256, 4) void passB_fused(
    const unsigned short* __restrict__ G1a, const unsigned short* __restrict__ G1b,
    const float* __restrict__ f, const int* __restrict__ idx,
    const unsigned short* __restrict__ w2s, const unsigned short* __restrict__ w3s,
    const float* __restrict__ sh2, const float* __restrict__ sh3,
    float* __restrict__ out) {
    __shared__ __attribute__((aligned(16))) unsigned short s_h1[16 * 72];
    __shared__ float s_out[32 * 133];

    const int tid  = threadIdx.x;
    const int wave = tid >> 6;
    const int lane = tid & 63;
    const int c15  = lane & 15;
    const int q    = lane >> 4;
    const int pg   = tid >> 4;
    const int cg   = tid & 15;

    const int t0  = blockIdx.x * G;
    const int b   = t0 / TPB;
    const int nb0 = (t0 - b * TPB) * 16;

    float sh2v[2], sh3v[2];
    bf16x8 bw2[2][2], bw3[2][2];
#pragma unroll
    for (int nt = 0; nt < 2; ++nt) {
        const int d = wave * 32 + nt * 16 + c15;
        sh2v[nt] = sh2[d];
        sh3v[nt] = sh3[d];
#pragma unroll
        for (int ks = 0; ks < 2; ++ks) {
            bw2[nt][ks] = __builtin_bit_cast(bf16x8, *(const uint4*)(w2s + d * 64 + ks * 32 + q * 8));
            bw3[nt][ks] = __builtin_bit_cast(bf16x8, *(const uint4*)(w3s + d * 64 + ks * 32 + q * 8));
        }
    }

    const unsigned short* Gha = G1a + (size_t)b * Nn * 32;
    const unsigned short* Ghb = G1b + (size_t)b * Nn * 32;
    const unsigned short* Gh  = (cg < 8) ? Gha : Ghb;
    const int cgo = (cg & 7) * 4;
    const float* fb0 = f + (size_t)b * Cc * Nn;
    const int* idxp = idx + ((size_t)b * Nn + nb0) * Kk;

    int myidx = idxp[tid];

    for (int g = 0; g < G; ++g) {
        const int n0 = nb0 + g * 16;
        const int myidxN = (g + 1 < G) ? idxp[(g + 1) * 256 + tid] : 0;

        const float* fown = fb0 + n0 + c15;
        us8 F0, F1;
#pragma unroll
        for (int jj = 0; jj < 8; ++jj) F0[jj] = f2bf(fown[(size_t)(q * 8 + jj) * Nn]);
#pragma unroll
        for (int jj = 0; jj < 8; ++jj) F1[jj] = f2bf(fown[(size_t)(32 + q * 8 + jj) * Nn]);

        float a0 = 0.f, a1 = 0.f, a2 = 0.f, a3 = 0.f;
#pragma unroll
        for (int k = 0; k < 16; ++k) {
            const int nb = __shfl(myidx, (pg & 3) * 16 + k, 64);
            const uint2 d2 = *(const uint2*)(Gh + (size_t)nb * 32 + cgo);
            a0 += __builtin_bit_cast(float, d2.x << 16);
            a1 += __builtin_bit_cast(float, d2.x & 0xffff0000u);
            a2 += __builtin_bit_cast(float, d2.y << 16);
            a3 += __builtin_bit_cast(float, d2.y & 0xffff0000u);
        }
        myidx = myidxN;

        __syncthreads();
        us4 hv;
        hv[0] = f2bf(a0); hv[1] = f2bf(a1); hv[2] = f2bf(a2); hv[3] = f2bf(a3);
        *(us4*)(s_h1 + pg * 72 + cg * 4) = hv;
        __syncthreads();

        const unsigned short* h1row = s_h1 + c15 * 72;
        const bf16x8 ah0 = __builtin_bit_cast(bf16x8, *(const uint4*)(h1row + q * 8));
        const bf16x8 ah1 = __builtin_bit_cast(bf16x8, *(const uint4*)(h1row + 32 + q * 8));
        const bf16x8 af0 = __builtin_bit_cast(bf16x8, F0);
        const bf16x8 af1 = __builtin_bit_cast(bf16x8, F1);

        const int prow = (g & 1) * 16;
#pragma unroll
        for (int nt = 0; nt < 2; ++nt) {
            f32x4 h2 = {sh2v[nt], sh2v[nt], sh2v[nt], sh2v[nt]};
            f32x4 s3 = {sh3v[nt], sh3v[nt], sh3v[nt], sh3v[nt]};
            h2 = __builtin_amdgcn_mfma_f32_16x16x32_bf16(ah0, bw2[nt][0], h2, 0, 0, 0);
            h2 = __builtin_amdgcn_mfma_f32_16x16x32_bf16(ah1, bw2[nt][1], h2, 0, 0, 0);
            s3 = __builtin_amdgcn_mfma_f32_16x16x32_bf16(af0, bw3[nt][0], s3, 0, 0, 0);
            s3 = __builtin_amdgcn_mfma_f32_16x16x32_bf16(af1, bw3[nt][1], s3, 0, 0, 0);
            const int d = wave * 32 + nt * 16 + c15;
#pragma unroll
            for (int r = 0; r < 4; ++r)
                s_out[(prow + q * 4 + r) * 133 + d] = fmaxf(h2[r], 0.f) + fmaxf(s3[r], 0.f);
        }
        __syncthreads();

        if (g & 1) {
            const int np = n0 - 16;
            const int dd = tid >> 3;
            const int ck = tid & 7;
#pragma unroll
            for (int r4 = 0; r4 < 4; ++r4) {
                const int d = r4 * 32 + dd;
                f32x4 v;
#pragma unroll
                for (int i = 0; i < 4; ++i) v[i] = s_out[(ck * 4 + i) * 133 + d];
                __builtin_nontemporal_store(v, (f32x4*)(out + ((size_t)b * Dd + d) * Nn + np + ck * 4));
            }
        }
    }
}

extern "C" void kernel_launch(void* const* d_in, const int* in_sizes, int n_in,
                              void* d_out, int out_size, void* d_ws, size_t ws_size,
                              hipStream_t stream) {
    const float* feature = (const float*)d_in[0];
    const int*   neigh   = (const int*)d_in[1];
    const float* w1 = (const float*)d_in[2];
    const float* g1 = (const float*)d_in[3];
    const float* b1 = (const float*)d_in[4];
    const float* m1 = (const float*)d_in[5];
    const float* v1 = (const float*)d_in[6];
    const float* w2 = (const float*)d_in[7];
    const float* g2 = (const float*)d_in[8];
    const float* b2 = (const float*)d_in[9];
    const float* m2 = (const float*)d_in[10];
    const float* v2 = (const float*)d_in[11];
    const float* w3 = (const float*)d_in[12];
    const float* g3 = (const float*)d_in[13];
    const float* b3 = (const float*)d_in[14];
    const float* m3 = (const float*)d_in[15];
    const float* v3 = (const float*)d_in[16];
    float* out = (float*)d_out;

    const size_t SZ_HALF = (size_t)Bb * Nn * 32 * 2;      // 10,485,760 B per G1 half
    const size_t SZ_H1   = (size_t)Bb * Nn * 64 * 2;      // 20,971,520 B
    const size_t SZ_W    = 42240;                          // weights + shifts

    char* ws = (char*)d_ws;
    unsigned short* G1a = (unsigned short*)ws;
    unsigned short* G1b = (unsigned short*)(ws + SZ_HALF);
    const bool split = ws_size >= 2 * SZ_HALF + SZ_H1 + SZ_W;
    unsigned short* h1 = (unsigned short*)(ws + 2 * SZ_HALF);
    char* wbase = ws + (split ? 2 * SZ_HALF + SZ_H1 : 2 * SZ_HALF);

    unsigned short* w1s = (unsigned short*)wbase;
    unsigned short* w2s = (unsigned short*)(wbase + 8192);
    unsigned short* w3s = (unsigned short*)(wbase + 24576);
    float* sh1 = (float*)(wbase + 40960);
    float* sh2 = (float*)(wbase + 41216);
    float* sh3 = (float*)(wbase + 41728);

    prep_weights<<<80, 256, 0, stream>>>(w1, g1, b1, m1, v1, w2, g2, b2, m2, v2,
                                         w3, g3, b3, m3, v3, w1s, w2s, w3s, sh1, sh2, sh3);
    passA<<<Bb * 640, 256, 0, stream>>>(feature, w1s, sh1, G1a, G1b);
    if (split) {
        const int ggrid = 8 * (GB_BPB / 2);               // 2560
        gatherH<<<ggrid, 256, 0, stream>>>(G1a, neigh, h1, 0);
        gatherH<<<ggrid, 256, 0, stream>>>(G1b, neigh, h1, 32);
        passC<<<(Bb * TPB) / G, 256, 0, stream>>>(h1, feature, w2s, w3s, sh2, sh3, out);
    } else {
        passB_fused<<<(Bb * TPB) / G, 256, 0, stream>>>(G1a, G1b, feature, neigh,
                                                        w2s, w3s, sh2, sh3, out);
    }
}

// Round 5
// 209.871 us; speedup vs baseline: 1.2646x; 1.2646x over previous
//
#include <hip/hip_runtime.h>

#define EPSV 1e-5f
constexpr int Bb = 4, Cc = 64, Nn = 40960, Kk = 16, Dd = 128;
constexpr int G = 4;                       // point-tiles per block in pass B (even!)
constexpr int TPB = Nn / 16;               // tiles per batch = 2560

typedef float f32x4 __attribute__((ext_vector_type(4)));
typedef __bf16 bf16x8 __attribute__((ext_vector_type(8)));
typedef unsigned short us8 __attribute__((ext_vector_type(8)));
typedef unsigned short us4 __attribute__((ext_vector_type(4)));

__device__ inline unsigned short f2bf(float x) {
    unsigned u = __builtin_bit_cast(unsigned, x);
    u += 0x7FFFu + ((u >> 16) & 1u);   // RNE
    return (unsigned short)(u >> 16);
}

// ---------------------------------------------------------------------------
// Prep: fold BN scale into bf16 weights, precompute shifts.
__global__ __launch_bounds__(256) void prep_weights(
    const float* __restrict__ w1, const float* __restrict__ g1, const float* __restrict__ b1,
    const float* __restrict__ m1, const float* __restrict__ v1,
    const float* __restrict__ w2, const float* __restrict__ g2, const float* __restrict__ b2,
    const float* __restrict__ m2, const float* __restrict__ v2,
    const float* __restrict__ w3, const float* __restrict__ g3, const float* __restrict__ b3,
    const float* __restrict__ m3, const float* __restrict__ v3,
    unsigned short* __restrict__ w1s, unsigned short* __restrict__ w2s, unsigned short* __restrict__ w3s,
    float* __restrict__ sh1, float* __restrict__ sh2, float* __restrict__ sh3) {
    const int e = blockIdx.x * 256 + threadIdx.x;
    if (e < 4096) {
        const int o = e >> 6;
        const float sc = g1[o] * rsqrtf(v1[o] + EPSV);
        w1s[e] = f2bf(w1[e] * sc);
    } else if (e < 12288) {
        const int i = e - 4096, o = i >> 6;
        const float sc = g2[o] * rsqrtf(v2[o] + EPSV);
        w2s[i] = f2bf(w2[i] * sc);
    } else if (e < 20480) {
        const int i = e - 12288, o = i >> 6;
        const float sc = g3[o] * rsqrtf(v3[o] + EPSV);
        w3s[i] = f2bf(w3[i] * sc);
    }
    if (e < 64) sh1[e] = b1[e] - m1[e] * (g1[e] * rsqrtf(v1[e] + EPSV));
    else if (e < 192) { const int d = e - 64;  sh2[d] = b2[d] - m2[d] * (g2[d] * rsqrtf(v2[d] + EPSV)); }
    else if (e < 320) { const int d = e - 192; sh3[d] = b3[d] - m3[d] * (g3[d] * rsqrtf(v3[d] + EPSV)); }
}

// ---------------------------------------------------------------------------
// Pass A: G1 = relu(sc1 * (W1 . f) + sh1), stored (B,N,64) bf16.
// ALSO stores f_t[B][N][64] bf16: the transposed feature A-fragments, in the
// exact MFMA A-frag layout passB's W3 skip path consumes (wave w stores its
// mt==w fragments -> each (point, ch-chunk) written exactly once).
__global__ __launch_bounds__(256) void passA(const float* __restrict__ f,
                                             const unsigned short* __restrict__ w1s,
                                             const float* __restrict__ sh1,
                                             unsigned short* __restrict__ G1,
                                             unsigned short* __restrict__ f_t) {
    __shared__ float s[64 * 65];                            // [ch][pt]
    __shared__ __attribute__((aligned(16))) unsigned short sg1[64 * 72];  // [pt][ch]

    const int tid = threadIdx.x, w = tid >> 6, lane = tid & 63;
    const int c15 = lane & 15, q = lane >> 4;
    const int b = blockIdx.x / 640;
    const int n0 = (blockIdx.x % 640) * 64;

    // load fp32 tile: [64 ch][64 pts] (coalesced: 64 consecutive floats/row)
    const float* src = f + ((size_t)b * Cc + w * 16) * Nn + n0 + lane;
#pragma unroll
    for (int i = 0; i < 16; ++i) s[(w * 16 + i) * 65 + lane] = src[(size_t)i * Nn];

    // weight B-frags: out-channel o1 = w*16 + c15
    const int o1 = w * 16 + c15;
    const float sh1v = sh1[o1];
    bf16x8 bw1[2];
#pragma unroll
    for (int ks = 0; ks < 2; ++ks)
        bw1[ks] = __builtin_bit_cast(bf16x8, *(const uint4*)(w1s + o1 * 64 + ks * 32 + q * 8));
    __syncthreads();

#pragma unroll
    for (int mt = 0; mt < 4; ++mt) {
        const int pt = mt * 16 + c15;
        us8 A0, A1;
#pragma unroll
        for (int j = 0; j < 8; ++j) A0[j] = f2bf(s[(q * 8 + j) * 65 + pt]);
#pragma unroll
        for (int j = 0; j < 8; ++j) A1[j] = f2bf(s[(32 + q * 8 + j) * 65 + pt]);

        // store transposed-f A-frags (each wave owns mt == w)
        if (mt == w) {
            unsigned short* dst = f_t + ((size_t)b * Nn + n0 + pt) * 64;
            *(uint4*)(dst + q * 8)      = __builtin_bit_cast(uint4, A0);
            *(uint4*)(dst + 32 + q * 8) = __builtin_bit_cast(uint4, A1);
        }

        f32x4 g = {0.f, 0.f, 0.f, 0.f};
        g = __builtin_amdgcn_mfma_f32_16x16x32_bf16(__builtin_bit_cast(bf16x8, A0), bw1[0], g, 0, 0, 0);
        g = __builtin_amdgcn_mfma_f32_16x16x32_bf16(__builtin_bit_cast(bf16x8, A1), bw1[1], g, 0, 0, 0);
#pragma unroll
        for (int r = 0; r < 4; ++r)
            sg1[(mt * 16 + q * 4 + r) * 72 + o1] = f2bf(fmaxf(g[r] + sh1v, 0.f));
    }
    __syncthreads();

    // coalesced store: thread (p = tid>>2, ck = tid&3) writes 32 B of row p
    {
        const int p = tid >> 2, ck = tid & 3;
        const uint4 v0 = *(const uint4*)(sg1 + p * 72 + ck * 16);
        const uint4 v1 = *(const uint4*)(sg1 + p * 72 + ck * 16 + 8);
        unsigned short* dst = G1 + ((size_t)b * Nn + n0 + p) * 64 + ck * 16;
        *(uint4*)dst = v0;
        *(uint4*)(dst + 8) = v1;
    }
}

// ---------------------------------------------------------------------------
// Pass B (fused, round-3 validated skeleton). Changes vs round 3:
// (1) skip-path A-frags read from f_t as two contiguous uint4 loads (the
//     passC-proven pattern) instead of 32 strided scalar f loads + f2bf;
// (2) XCD-batch affinity: xcd = bid&7 handles only batch (xcd>>1), so each
//     XCD's gather working set is one batch's G1 (5.24 MB ~ L2) not 21 MB.
__global__ __launch_bounds__(256, 4) void passB(
    const unsigned short* __restrict__ G1, const unsigned short* __restrict__ f_t,
    const int* __restrict__ idx,
    const unsigned short* __restrict__ w2s, const unsigned short* __restrict__ w3s,
    const float* __restrict__ sh2, const float* __restrict__ sh3,
    float* __restrict__ out) {
    __shared__ __attribute__((aligned(16))) unsigned short s_h1[16 * 72];   // 2304 B
    __shared__ float s_out[32 * 133];                                       // 17024 B

    const int tid  = threadIdx.x;
    const int wave = tid >> 6;
    const int lane = tid & 63;
    const int c15  = lane & 15;
    const int q    = lane >> 4;
    const int pg   = tid >> 4;              // gather-phase point 0..15
    const int cg   = tid & 15;              // gather-phase channel group (4 ch)

    // XCD-batch affinity (dispatch round-robins blockIdx over the 8 XCDs)
    const int xcd = blockIdx.x & 7;
    const int jb  = blockIdx.x >> 3;        // 0..319
    const int b   = xcd >> 1;               // 2 XCDs per batch
    const int nb0 = (((xcd & 1) * 320) + jb) * (G * 16);

    // weight B-frags (register-resident, bf16 pre-scaled)
    float sh2v[2], sh3v[2];
    bf16x8 bw2[2][2], bw3[2][2];
#pragma unroll
    for (int nt = 0; nt < 2; ++nt) {
        const int d = wave * 32 + nt * 16 + c15;
        sh2v[nt] = sh2[d];
        sh3v[nt] = sh3[d];
#pragma unroll
        for (int ks = 0; ks < 2; ++ks) {
            bw2[nt][ks] = __builtin_bit_cast(bf16x8, *(const uint4*)(w2s + d * 64 + ks * 32 + q * 8));
            bw3[nt][ks] = __builtin_bit_cast(bf16x8, *(const uint4*)(w3s + d * 64 + ks * 32 + q * 8));
        }
    }

    const unsigned short* G1b = G1 + (size_t)b * Nn * 64;
    const unsigned short* ftb = f_t + (size_t)b * Nn * 64;
    const int* idxp = idx + ((size_t)b * Nn + nb0) * Kk;

    int myidx = idxp[tid];                  // tile 0's idx row

    for (int g = 0; g < G; ++g) {
        const int n0 = nb0 + g * 16;

        // prefetch next tile's idx row (hides idx-load latency under this tile)
        const int myidxN = (g + 1 < G) ? idxp[(g + 1) * 256 + tid] : 0;

        // skip-path A-frags: contiguous bf16 rows from f_t (no strided loads)
        const unsigned short* ftrow = ftb + (size_t)(n0 + c15) * 64;
        const bf16x8 af0 = __builtin_bit_cast(bf16x8, *(const uint4*)(ftrow + q * 8));
        const bf16x8 af1 = __builtin_bit_cast(bf16x8, *(const uint4*)(ftrow + 32 + q * 8));

        // gather + sum: thread (pg, cg) accumulates 4 channels over 16 nbrs.
        // G1 rows are already relu'd (passA), so this is pure adds.
        float a0 = 0.f, a1 = 0.f, a2 = 0.f, a3 = 0.f;
#pragma unroll
        for (int k = 0; k < 16; ++k) {
            const int nb = __shfl(myidx, (pg & 3) * 16 + k, 64);
            const uint2 d2 = *(const uint2*)(G1b + (size_t)nb * 64 + cg * 4);
            a0 += __builtin_bit_cast(float, d2.x << 16);
            a1 += __builtin_bit_cast(float, d2.x & 0xffff0000u);
            a2 += __builtin_bit_cast(float, d2.y << 16);
            a3 += __builtin_bit_cast(float, d2.y & 0xffff0000u);
        }
        myidx = myidxN;

        __syncthreads();                     // prev iter's s_h1/s_out reads done
        us4 hv;
        hv[0] = f2bf(a0); hv[1] = f2bf(a1); hv[2] = f2bf(a2); hv[3] = f2bf(a3);
        *(us4*)(s_h1 + pg * 72 + cg * 4) = hv;
        __syncthreads();

        // GEMM2 (W2 . h1) + skip (W3 . f_own)
        const unsigned short* h1row = s_h1 + c15 * 72;
        const bf16x8 ah0 = __builtin_bit_cast(bf16x8, *(const uint4*)(h1row + q * 8));
        const bf16x8 ah1 = __builtin_bit_cast(bf16x8, *(const uint4*)(h1row + 32 + q * 8));

        const int prow = (g & 1) * 16;       // s_out row base for this tile
#pragma unroll
        for (int nt = 0; nt < 2; ++nt) {
            f32x4 h2 = {sh2v[nt], sh2v[nt], sh2v[nt], sh2v[nt]};
            f32x4 s3 = {sh3v[nt], sh3v[nt], sh3v[nt], sh3v[nt]};
            h2 = __builtin_amdgcn_mfma_f32_16x16x32_bf16(ah0, bw2[nt][0], h2, 0, 0, 0);
            h2 = __builtin_amdgcn_mfma_f32_16x16x32_bf16(ah1, bw2[nt][1], h2, 0, 0, 0);
            s3 = __builtin_amdgcn_mfma_f32_16x16x32_bf16(af0, bw3[nt][0], s3, 0, 0, 0);
            s3 = __builtin_amdgcn_mfma_f32_16x16x32_bf16(af1, bw3[nt][1], s3, 0, 0, 0);
            const int d = wave * 32 + nt * 16 + c15;
#pragma unroll
            for (int r = 0; r < 4; ++r)
                s_out[(prow + q * 4 + r) * 133 + d] = fmaxf(h2[r], 0.f) + fmaxf(s3[r], 0.f);
        }
        __syncthreads();

        // full-line nontemporal store every 2 tiles:
        // 8 lanes x 16 B cover one 128-B line of row d (32 points); 4 passes.
        if (g & 1) {
            const int np = n0 - 16;          // pair base point (line-aligned)
            const int dd = tid >> 3;         // 0..31: row within pass
            const int ck = tid & 7;          // 16-B chunk within line
#pragma unroll
            for (int r4 = 0; r4 < 4; ++r4) {
                const int d = r4 * 32 + dd;
                f32x4 v;
#pragma unroll
                for (int i = 0; i < 4; ++i) v[i] = s_out[(ck * 4 + i) * 133 + d];
                __builtin_nontemporal_store(v, (f32x4*)(out + ((size_t)b * Dd + d) * Nn + np + ck * 4));
            }
        }
    }
}

extern "C" void kernel_launch(void* const* d_in, const int* in_sizes, int n_in,
                              void* d_out, int out_size, void* d_ws, size_t ws_size,
                              hipStream_t stream) {
    const float* feature = (const float*)d_in[0];
    const int*   neigh   = (const int*)d_in[1];
    const float* w1 = (const float*)d_in[2];
    const float* g1 = (const float*)d_in[3];
    const float* b1 = (const float*)d_in[4];
    const float* m1 = (const float*)d_in[5];
    const float* v1 = (const float*)d_in[6];
    const float* w2 = (const float*)d_in[7];
    const float* g2 = (const float*)d_in[8];
    const float* b2 = (const float*)d_in[9];
    const float* m2 = (const float*)d_in[10];
    const float* v2 = (const float*)d_in[11];
    const float* w3 = (const float*)d_in[12];
    const float* g3 = (const float*)d_in[13];
    const float* b3 = (const float*)d_in[14];
    const float* m3 = (const float*)d_in[15];
    const float* v3 = (const float*)d_in[16];
    float* out = (float*)d_out;

    const size_t SZ_G1 = (size_t)Bb * Nn * 64 * 2;        // 20,971,520 B
    const size_t SZ_FT = (size_t)Bb * Nn * 64 * 2;        // 20,971,520 B

    char* ws = (char*)d_ws;
    unsigned short* G1  = (unsigned short*)ws;
    unsigned short* f_t = (unsigned short*)(ws + SZ_G1);
    char* wbase = ws + SZ_G1 + SZ_FT;

    unsigned short* w1s = (unsigned short*)wbase;
    unsigned short* w2s = (unsigned short*)(wbase + 8192);
    unsigned short* w3s = (unsigned short*)(wbase + 24576);
    float* sh1 = (float*)(wbase + 40960);
    float* sh2 = (float*)(wbase + 41216);
    float* sh3 = (float*)(wbase + 41728);

    prep_weights<<<80, 256, 0, stream>>>(w1, g1, b1, m1, v1, w2, g2, b2, m2, v2,
                                         w3, g3, b3, m3, v3, w1s, w2s, w3s, sh1, sh2, sh3);
    passA<<<Bb * 640, 256, 0, stream>>>(feature, w1s, sh1, G1, f_t);
    passB<<<(Bb * TPB) / G, 256, 0, stream>>>(G1, f_t, neigh, w2s, w3s,
                                              sh2, sh3, out);
}